// Round 14
// baseline (492.897 us; speedup 1.0000x reference)
//
#include <hip/hip_runtime.h>
#include <cmath>

#define T 512
#define HID 64
#define BLK_B 32       // two halves of 16 batch, software-pipelined per wave
#define TS 32          // timesteps per staged x-chunk
#define LOG2E 1.44269504f

typedef __attribute__((ext_vector_type(8))) _Float16 f16x8;
typedef __attribute__((ext_vector_type(4))) float f32x4;

__device__ __forceinline__ float fast_rcp(float x) { return __builtin_amdgcn_rcpf(x); }
__device__ __forceinline__ float fast_exp2(float x) { return __builtin_amdgcn_exp2f(x); }
__device__ __forceinline__ float sig_f(float x) {
    return fast_rcp(1.0f + fast_exp2(-LOG2E * x));
}
__device__ __forceinline__ float th_f(float x) {
    return 1.0f - 2.0f * fast_rcp(1.0f + fast_exp2((2.0f * LOG2E) * x));
}

#define MFMA(a, b, c) __builtin_amdgcn_mfma_f32_16x16x32_f16((a), (b), (c), 0, 0, 0)

// Intra-wave pipelined LSTM (r13 post-mortem: inter-wave role split loses to
// sync cost; this keeps MFMA ∥ trans overlap inside each wave). Per phase a
// wave issues the MFMA chain for one batch-half (consumed NEXT phase) while
// activating the other half's gates from registers (produced LAST phase).
// Gates never touch LDS. Verified 16x16x32 lane mapping (r7-r12).
__global__ __launch_bounds__(256) void lstm_pipe_kernel(
    const float* __restrict__ x,      // [B, T, 8]
    const float* __restrict__ W_ih,   // [256, 8]
    const float* __restrict__ W_hh,   // [256, 64]
    const float* __restrict__ b_ih,   // [256]
    const float* __restrict__ b_hh,   // [256]
    const float* __restrict__ W_fc,   // [2, 64]
    const float* __restrict__ b_fc,   // [2]
    float* __restrict__ out)          // [B, 2]
{
    // 63KB arena -> allocator targets 2 blocks/CU -> 256-VGPR budget for
    // ~125-reg live set (occupancy-target model, rounds 3-13).
    __shared__ alignas(16) _Float16 arena[32256];            // 63 KB
    _Float16* xb    = arena;                  // [TS][32][8] f16 x chunk
    _Float16* hbase = arena + 8192;           // [2 halves][16][72] f16 h

    const int tid  = threadIdx.x;
    const int w    = tid >> 6;        // wave 0..3 -> j-block [16w,16w+16)
    const int lane = tid & 63;
    const int colb = lane & 15;       // batch col within half
    const int grp  = lane >> 4;       // k-slice / row-quad group
    const int batch0 = blockIdx.x * BLK_B;

    // ---- persistent A-frags: W_hh f16 (2 k-tiles), W_ih packed tile ----
#define DECL_Q(q) f16x8 whi##q##_0, whi##q##_1, wih##q; f32x4 bias##q;
    DECL_Q(0) DECL_Q(1) DECL_Q(2) DECL_Q(3)
#undef DECL_Q
    f16x8 zz;
    #pragma unroll
    for (int e = 0; e < 8; ++e) zz[e] = (_Float16)0.0f;

#define LOAD_Q(q) {                                                        \
        int gate = 64 * q + 16 * w + colb;                                 \
        const float* wr = W_hh + gate * 64 + grp * 8;                      \
        _Pragma("unroll")                                                  \
        for (int e = 0; e < 8; ++e) {                                      \
            whi##q##_0[e] = (_Float16)wr[e];                               \
            whi##q##_1[e] = (_Float16)wr[32 + e];                          \
        }                                                                  \
        const float* wi = W_ih + gate * 8;                                 \
        f16x8 ih;                                                          \
        _Pragma("unroll")                                                  \
        for (int e = 0; e < 8; ++e) ih[e] = (_Float16)wi[e];               \
        wih##q = (grp == 0) ? ih : zz;                                     \
        int gb = 64 * q + 16 * w + grp * 4;                                \
        bias##q.x = b_ih[gb + 0] + b_hh[gb + 0];                           \
        bias##q.y = b_ih[gb + 1] + b_hh[gb + 1];                           \
        bias##q.z = b_ih[gb + 2] + b_hh[gb + 2];                           \
        bias##q.w = b_ih[gb + 3] + b_hh[gb + 3];                           \
    }
    LOAD_Q(0) LOAD_Q(1) LOAD_Q(2) LOAD_Q(3)
#undef LOAD_Q

    // zero both h halves: 2304 f16 / 256 threads = 9 each
    #pragma unroll
    for (int i = 0; i < 9; ++i) hbase[tid * 9 + i] = (_Float16)0.0f;

    f32x4 c0v = {0, 0, 0, 0};     // c states, half 0
    f32x4 c1v = {0, 0, 0, 0};     // c states, half 1
    f32x4 g00, g01, g02, g03;     // gates half 0 (register-resident)
    f32x4 g10, g11, g12, g13;     // gates half 1

    const int rdoff = colb * 72 + grp * 8;
    const int wroff = colb * 72 + 16 * w + grp * 4;

    // ---- MFMA sub-phase: G# = gates(half, tmod) ----
#define MPH(hf, tmod, G0, G1, G2, G3) {                                    \
        const _Float16* hb = hbase + (hf) * 1152 + rdoff;                  \
        f16x8 bh0 = *(const f16x8*)(hb);                                   \
        f16x8 bh1 = *(const f16x8*)(hb + 32);                              \
        f16x8 bx  = *(const f16x8*)(xb + (tmod) * 256 + (hf) * 128 + colb * 8); \
        G0 = MFMA(wih0, bx, bias0);                                        \
        G0 = MFMA(whi0_0, bh0, G0);  G0 = MFMA(whi0_1, bh1, G0);           \
        G1 = MFMA(wih1, bx, bias1);                                        \
        G1 = MFMA(whi1_0, bh0, G1);  G1 = MFMA(whi1_1, bh1, G1);           \
        G2 = MFMA(wih2, bx, bias2);                                        \
        G2 = MFMA(whi2_0, bh0, G2);  G2 = MFMA(whi2_1, bh1, G2);           \
        G3 = MFMA(wih3, bx, bias3);                                        \
        G3 = MFMA(whi3_0, bh0, G3);  G3 = MFMA(whi3_1, bh1, G3);           \
    }

    // ---- activation sub-phase: registers G# -> c,h; h -> LDS ----
#define APH(G0, G1, G2, G3, CV, hf) {                                      \
        float gi0 = sig_f(G0.x), gi1 = sig_f(G0.y), gi2 = sig_f(G0.z), gi3 = sig_f(G0.w); \
        float gf0 = sig_f(G1.x), gf1 = sig_f(G1.y), gf2 = sig_f(G1.z), gf3 = sig_f(G1.w); \
        float gg0 = th_f(G2.x),  gg1 = th_f(G2.y),  gg2 = th_f(G2.z),  gg3 = th_f(G2.w);  \
        float go0 = sig_f(G3.x), go1 = sig_f(G3.y), go2 = sig_f(G3.z), go3 = sig_f(G3.w); \
        CV.x = fmaf(gf0, CV.x, gi0 * gg0);                                 \
        CV.y = fmaf(gf1, CV.y, gi1 * gg1);                                 \
        CV.z = fmaf(gf2, CV.z, gi2 * gg2);                                 \
        CV.w = fmaf(gf3, CV.w, gi3 * gg3);                                 \
        float h0 = go0 * th_f(CV.x);                                       \
        float h1 = go1 * th_f(CV.y);                                       \
        float h2 = go2 * th_f(CV.z);                                       \
        float h3 = go3 * th_f(CV.w);                                       \
        auto p01 = __builtin_amdgcn_cvt_pkrtz(h0, h1);                     \
        auto p23 = __builtin_amdgcn_cvt_pkrtz(h2, h3);                     \
        uint2 st;                                                          \
        st.x = __builtin_bit_cast(unsigned int, p01);                      \
        st.y = __builtin_bit_cast(unsigned int, p23);                      \
        *(uint2*)(hbase + (hf) * 1152 + wroff) = st;                       \
    }

    // ---- x staging: 32 t x 32 b, f16; 256 threads x 4 vec8 ----
#define STAGE(tstart) {                                                    \
        int sb = tid >> 3, st_ = tid & 7;                                  \
        _Pragma("unroll")                                                  \
        for (int r = 0; r < 4; ++r) {                                      \
            int tt = st_ + r * 8;                                          \
            const float* xg = x + ((size_t)(batch0 + sb) * T + (tstart) + tt) * 8; \
            f16x8 v;                                                       \
            _Pragma("unroll")                                              \
            for (int e = 0; e < 8; ++e) v[e] = (_Float16)xg[e];            \
            *(f16x8*)(xb + (tt * 32 + sb) * 8) = v;                        \
        }                                                                  \
    }

    STAGE(0)
    __syncthreads();                // x chunk 0 + h zero-init visible

    // prologue: gates half0 @ t=0 (h0 = 0)
    MPH(0, 0, g00, g01, g02, g03)
    __syncthreads();

    #pragma unroll 1
    for (int t = 0; t < T; ++t) {
        // phase A: activate half0 gates(t) -> h0(t)  ∥  MFMA half1 gates(t)
        APH(g00, g01, g02, g03, c0v, 0)
        MPH(1, t & (TS - 1), g10, g11, g12, g13)
        __syncthreads();
        if (t == T - 1) break;
        if (((t + 1) & (TS - 1)) == 0) {
            STAGE(t + 1)
            __syncthreads();
        }
        // phase B: activate half1 gates(t) -> h1(t)  ∥  MFMA half0 gates(t+1)
        APH(g10, g11, g12, g13, c1v, 1)
        MPH(0, (t + 1) & (TS - 1), g00, g01, g02, g03)
        __syncthreads();
    }
    // epilogue: half1 gates(T-1) -> h1(T-1)
    APH(g10, g11, g12, g13, c1v, 1)
    __syncthreads();

    // ---- final FC: thread -> (b = tid>>3 of 32, 8 j's); 8-thread reduce ----
    {
        int b = tid >> 3, j0 = (tid & 7) * 8;
        const _Float16* ph = hbase + (b >> 4) * 1152 + (b & 15) * 72 + j0;
        float s0 = 0.0f, s1 = 0.0f;
        #pragma unroll
        for (int e = 0; e < 8; ++e) {
            float hv = (float)ph[e];
            s0 = fmaf(hv, W_fc[j0 + e], s0);
            s1 = fmaf(hv, W_fc[64 + j0 + e], s1);
        }
        #pragma unroll
        for (int off = 1; off < 8; off <<= 1) {
            s0 += __shfl_xor(s0, off, 64);
            s1 += __shfl_xor(s1, off, 64);
        }
        if ((tid & 7) == 0) {
            out[(size_t)(batch0 + b) * 2 + 0] = s0 + b_fc[0];
            out[(size_t)(batch0 + b) * 2 + 1] = s1 + b_fc[1];
        }
    }
#undef MPH
#undef APH
#undef STAGE
}

extern "C" void kernel_launch(void* const* d_in, const int* in_sizes, int n_in,
                              void* d_out, int out_size, void* d_ws, size_t ws_size,
                              hipStream_t stream) {
    const float* x    = (const float*)d_in[0];
    const float* W_ih = (const float*)d_in[1];
    const float* W_hh = (const float*)d_in[2];
    const float* b_ih = (const float*)d_in[3];
    const float* b_hh = (const float*)d_in[4];
    const float* W_fc = (const float*)d_in[5];
    const float* b_fc = (const float*)d_in[6];
    float* out = (float*)d_out;

    dim3 grid(8192 / BLK_B);   // 256 blocks = 1 per CU
    dim3 block(256);
    lstm_pipe_kernel<<<grid, block, 0, stream>>>(x, W_ih, W_hh, b_ih, b_hh,
                                                 W_fc, b_fc, out);
}

// Round 15
// 333.370 us; speedup vs baseline: 1.4785x; 1.4785x over previous
//
#include <hip/hip_runtime.h>
#include <cmath>

#define T 512
#define HID 64
#define BLK_B 16       // batch per block
#define TS 64          // timesteps per staged x-chunk
#define NCHUNK (T / TS)
#define LOG2E 1.44269504f

typedef __attribute__((ext_vector_type(8))) _Float16 f16x8;
typedef __attribute__((ext_vector_type(4))) float f32x4;

__device__ __forceinline__ float fast_rcp(float x) { return __builtin_amdgcn_rcpf(x); }
__device__ __forceinline__ float fast_exp2(float x) { return __builtin_amdgcn_exp2f(x); }
// PRE-SCALED activations: a already multiplied by -log2e (sig) / +2log2e (tanh)
__device__ __forceinline__ float sig_p(float a) {        // v_exp, add, v_rcp
    return fast_rcp(1.0f + fast_exp2(a));
}
__device__ __forceinline__ float th_p(float a) {         // v_exp, add, v_rcp, fma
    return 1.0f - 2.0f * fast_rcp(1.0f + fast_exp2(a));
}
// unscaled tanh (for c, which lives in the unscaled domain)
__device__ __forceinline__ float th_f(float x) {
    return 1.0f - 2.0f * fast_rcp(1.0f + fast_exp2((2.0f * LOG2E) * x));
}

#define MFMA(a, b, c) __builtin_amdgcn_mfma_f32_16x16x32_f16((a), (b), (c), 0, 0, 0)

// Round-15 = round-12 (best: 337us) + (1) gate-type log2e pre-scaling baked
// into W/bias (kills 16 VALU muls/thread-step) + (2) s_setprio(1) around the
// MFMA cluster (T5; two co-resident blocks/CU = independent-phase wave mix).
// Verified 16x16x32 lane mapping (r7-r12): A lane&15 = gate row, k = grp*8+e;
// B lane&15 = batch col; D col = lane&15, row = grp*4+reg.
__global__ __launch_bounds__(256, 2) void lstm_mfma_kernel(
    const float* __restrict__ x,      // [B, T, 8]
    const float* __restrict__ W_ih,   // [256, 8]
    const float* __restrict__ W_hh,   // [256, 64]
    const float* __restrict__ b_ih,   // [256]
    const float* __restrict__ b_hh,   // [256]
    const float* __restrict__ W_fc,   // [2, 64]
    const float* __restrict__ b_fc,   // [2]
    float* __restrict__ out)          // [B, 2]
{
    // Single 56KB arena: keeps backend occupancy target at 2 blocks/CU ->
    // 256-VGPR budget -> no spill (occupancy-target model, rounds 3-14).
    __shared__ alignas(16) _Float16 arena[28672];            // 56 KB
    _Float16* xb    = arena;                  // [TS][16][8]  f16 x chunk
    _Float16* hbase = arena + TS * BLK_B * 8; // [2][16][72]  h double-buffer

    const int tid  = threadIdx.x;
    const int w    = tid >> 6;        // wave 0..3 -> gate cols [16w,16w+16)
    const int lane = tid & 63;
    const int colb = lane & 15;       // batch col / A gate row
    const int grp  = lane >> 4;       // k-slice group 0..3
    const int batch0 = blockIdx.x * BLK_B;

    // ---- persistent A-frags: W_hh f16 (2 k-tiles), W_ih packed tile ----
#define DECL_Q(q) f16x8 whi##q##_0, whi##q##_1, wih##q; f32x4 bias##q;
    DECL_Q(0) DECL_Q(1) DECL_Q(2) DECL_Q(3)
#undef DECL_Q

    f16x8 zz;
    #pragma unroll
    for (int e = 0; e < 8; ++e) zz[e] = (_Float16)0.0f;

    // gate-type pre-scale: i,f,o (sigmoid) -> -log2e; g (tanh) -> +2 log2e
#define LOAD_Q(q, SC) {                                                    \
        const float sc = (SC);                                             \
        int gate = 64 * q + 16 * w + colb;                                 \
        const float* wr = W_hh + gate * 64 + grp * 8;                      \
        _Pragma("unroll")                                                  \
        for (int e = 0; e < 8; ++e) {                                      \
            whi##q##_0[e] = (_Float16)(sc * wr[e]);                        \
            whi##q##_1[e] = (_Float16)(sc * wr[32 + e]);                   \
        }                                                                  \
        const float* wi = W_ih + gate * 8;                                 \
        f16x8 ih;                                                          \
        _Pragma("unroll")                                                  \
        for (int e = 0; e < 8; ++e) ih[e] = (_Float16)(sc * wi[e]);        \
        wih##q = (grp == 0) ? ih : zz;   /* x term only in k-slot group 0 */ \
        int gb = 64 * q + 16 * w + grp * 4;                                \
        bias##q.x = sc * (b_ih[gb + 0] + b_hh[gb + 0]);                    \
        bias##q.y = sc * (b_ih[gb + 1] + b_hh[gb + 1]);                    \
        bias##q.z = sc * (b_ih[gb + 2] + b_hh[gb + 2]);                    \
        bias##q.w = sc * (b_ih[gb + 3] + b_hh[gb + 3]);                    \
    }
    LOAD_Q(0, -LOG2E)          // i : sigmoid
    LOAD_Q(1, -LOG2E)          // f : sigmoid
    LOAD_Q(2, 2.0f * LOG2E)    // g : tanh
    LOAD_Q(3, -LOG2E)          // o : sigmoid
#undef LOAD_Q

    // zero both h buffers: 2304 halves / 256 threads = 9 each
    #pragma unroll
    for (int i = 0; i < 9; ++i) hbase[tid * 9 + i] = (_Float16)0.0f;

    f32x4 cst = {0.0f, 0.0f, 0.0f, 0.0f};    // c for 4 owned states

    // ---- loop-invariant LDS pointers (buf0 = hbase, buf1 = hbase+1152) ----
    const int rdoff = colb * 72 + grp * 8;
    const int wroff = colb * 72 + 16 * w + grp * 4;
    const _Float16* rA0 = hbase + rdoff;          // buf0 k-tile0
    const _Float16* rA1 = hbase + rdoff + 32;     // buf0 k-tile1
    const _Float16* rB0 = hbase + 1152 + rdoff;   // buf1 k-tile0
    const _Float16* rB1 = hbase + 1152 + rdoff + 32;
    _Float16* wA = hbase + wroff;                 // write buf0
    _Float16* wB = hbase + 1152 + wroff;          // write buf1

    // one LSTM step: read h from (Rh0,Rh1), x from xp, write h to Wh
#define STEP(Rh0, Rh1, Wh, xp)                                            \
    {                                                                     \
        f16x8 bh0 = *(const f16x8*)(Rh0);                                 \
        f16x8 bh1 = *(const f16x8*)(Rh1);                                 \
        f16x8 bx  = *(const f16x8*)(xp);                                  \
        __builtin_amdgcn_s_setprio(1);                                    \
        f32x4 a0 = MFMA(wih0, bx, bias0);                                 \
        a0 = MFMA(whi0_0, bh0, a0);                                       \
        a0 = MFMA(whi0_1, bh1, a0);                                       \
        f32x4 a1 = MFMA(wih1, bx, bias1);                                 \
        a1 = MFMA(whi1_0, bh0, a1);                                       \
        a1 = MFMA(whi1_1, bh1, a1);                                       \
        f32x4 a2 = MFMA(wih2, bx, bias2);                                 \
        a2 = MFMA(whi2_0, bh0, a2);                                       \
        a2 = MFMA(whi2_1, bh1, a2);                                       \
        f32x4 a3 = MFMA(wih3, bx, bias3);                                 \
        a3 = MFMA(whi3_0, bh0, a3);                                       \
        a3 = MFMA(whi3_1, bh1, a3);                                       \
        __builtin_amdgcn_s_setprio(0);                                    \
        float gi0 = sig_p(a0.x), gi1 = sig_p(a0.y), gi2 = sig_p(a0.z), gi3 = sig_p(a0.w); \
        float gf0 = sig_p(a1.x), gf1 = sig_p(a1.y), gf2 = sig_p(a1.z), gf3 = sig_p(a1.w); \
        float gg0 = th_p(a2.x),  gg1 = th_p(a2.y),  gg2 = th_p(a2.z),  gg3 = th_p(a2.w);  \
        float go0 = sig_p(a3.x), go1 = sig_p(a3.y), go2 = sig_p(a3.z), go3 = sig_p(a3.w); \
        cst.x = fmaf(gf0, cst.x, gi0 * gg0);                              \
        cst.y = fmaf(gf1, cst.y, gi1 * gg1);                              \
        cst.z = fmaf(gf2, cst.z, gi2 * gg2);                              \
        cst.w = fmaf(gf3, cst.w, gi3 * gg3);                              \
        float h0 = go0 * th_f(cst.x);                                     \
        float h1 = go1 * th_f(cst.y);                                     \
        float h2 = go2 * th_f(cst.z);                                     \
        float h3 = go3 * th_f(cst.w);                                     \
        auto p01 = __builtin_amdgcn_cvt_pkrtz(h0, h1);                    \
        auto p23 = __builtin_amdgcn_cvt_pkrtz(h2, h3);                    \
        uint2 st;                                                         \
        st.x = __builtin_bit_cast(unsigned int, p01);                     \
        st.y = __builtin_bit_cast(unsigned int, p23);                     \
        *(uint2*)(Wh) = st;                                               \
        __syncthreads();                                                  \
    }

    #pragma unroll 1
    for (int tc = 0; tc < NCHUNK; ++tc) {
        // ---- stage + convert x chunk ----
        {
            int sb = tid >> 4, st = tid & 15;
            #pragma unroll
            for (int r = 0; r < 4; ++r) {
                int t = st + r * 16;
                const float* xg = x + ((size_t)(batch0 + sb) * T + (size_t)tc * TS + t) * 8;
                f16x8 v;
                #pragma unroll
                for (int e = 0; e < 8; ++e) v[e] = (_Float16)xg[e];
                *(f16x8*)(xb + (t * BLK_B + sb) * 8) = v;
            }
        }
        __syncthreads();

        const _Float16* xp = xb + colb * 8;
        #pragma unroll 1
        for (int tp = 0; tp < TS / 2; ++tp) {
            STEP(rA0, rA1, wB, xp)          // even step: buf0 -> buf1
            STEP(rB0, rB1, wA, xp + 128)    // odd step:  buf1 -> buf0
            xp += 256;
        }
    }
#undef STEP

    // ---- final FC (final h is in buf0): thread -> (b, 4 j's) ----
    {
        const _Float16* ph = hbase + (tid >> 4) * 72 + (tid & 15) * 4;
        int b = tid >> 4, q4 = (tid & 15) * 4;
        float h0 = (float)ph[0];
        float h1 = (float)ph[1];
        float h2 = (float)ph[2];
        float h3 = (float)ph[3];
        float s0 = h0 * W_fc[q4] + h1 * W_fc[q4 + 1] + h2 * W_fc[q4 + 2] + h3 * W_fc[q4 + 3];
        float s1 = h0 * W_fc[64 + q4] + h1 * W_fc[64 + q4 + 1] + h2 * W_fc[64 + q4 + 2] + h3 * W_fc[64 + q4 + 3];
        #pragma unroll
        for (int off = 1; off < 16; off <<= 1) {
            s0 += __shfl_xor(s0, off, 64);
            s1 += __shfl_xor(s1, off, 64);
        }
        if ((tid & 15) == 0) {
            out[(size_t)(batch0 + b) * 2 + 0] = s0 + b_fc[0];
            out[(size_t)(batch0 + b) * 2 + 1] = s1 + b_fc[1];
        }
    }
}

extern "C" void kernel_launch(void* const* d_in, const int* in_sizes, int n_in,
                              void* d_out, int out_size, void* d_ws, size_t ws_size,
                              hipStream_t stream) {
    const float* x    = (const float*)d_in[0];
    const float* W_ih = (const float*)d_in[1];
    const float* W_hh = (const float*)d_in[2];
    const float* b_ih = (const float*)d_in[3];
    const float* b_hh = (const float*)d_in[4];
    const float* W_fc = (const float*)d_in[5];
    const float* b_fc = (const float*)d_in[6];
    float* out = (float*)d_out;

    dim3 grid(8192 / BLK_B);   // 512 blocks = 2 per CU
    dim3 block(256);
    lstm_mfma_kernel<<<grid, block, 0, stream>>>(x, W_ih, W_hh, b_ih, b_hh,
                                                 W_fc, b_fc, out);
}